// Round 2
// baseline (12462.592 us; speedup 1.0000x reference)
//
#include <hip/hip_runtime.h>

typedef __attribute__((ext_vector_type(8))) short short8;
typedef __attribute__((ext_vector_type(4))) float f32x4;

static constexpr int B = 256, T = 250, Z = 128, H = 256, D = 512, KMIX = 20, P = 123;
static constexpr int PARAMS_N = B * T * P;        // 7,872,000
static constexpr int OUT_ZM = PARAMS_N;           // z_mean offset in d_out
static constexpr int OUT_ZL = PARAMS_N + B * Z;   // z_logvar offset

#define DEVI static __device__ __forceinline__

DEVI unsigned short f2bf(float f) {
    unsigned int u = __float_as_uint(f);
    u += 0x7fffu + ((u >> 16) & 1u);
    return (unsigned short)(u >> 16);
}
DEVI float bf2f(unsigned short s) { return __uint_as_float(((unsigned int)s) << 16); }
DEVI float sigm(float x) { return 1.0f / (1.0f + __expf(-x)); }
DEVI float tanh_(float x) {
    x = fminf(fmaxf(x, -15.0f), 15.0f);
    float e = __expf(2.0f * x);
    return (e - 1.0f) / (e + 1.0f);
}

// ---------------- zero-init (ws is poisoned 0xAA every replay) ----------------
__global__ void k_zero(float* c1, float* c2, unsigned short* h1, unsigned short* h2,
                       unsigned short* h1l, unsigned short* h2l) {
    int i = blockIdx.x * 256 + threadIdx.x;  // 65536 total = B*H
    c1[i] = 0.f; c2[i] = 0.f; h1[i] = 0; h2[i] = 0; h1l[i] = 0; h2l[i] = 0;
}

// ---------------- weight packing ----------------
// Wh [K=HID][4*HID] fp32 -> hi/lo [4*HID][HID] bf16, rows packed n = 4*d + g
template <int HID>
__global__ void k_pack_whT(const float* __restrict__ Wh, unsigned short* __restrict__ ohi,
                           unsigned short* __restrict__ olo) {
    constexpr int N4 = 4 * HID;
    __shared__ float tile[32][33];
    int c0 = blockIdx.x * 32, k0 = blockIdx.y * 32;
    int tx = threadIdx.x, ty = threadIdx.y;
#pragma unroll
    for (int ii = 0; ii < 4; ii++)
        tile[ty + 8 * ii][tx] = Wh[(size_t)(k0 + ty + 8 * ii) * N4 + c0 + tx];
    __syncthreads();
#pragma unroll
    for (int ii = 0; ii < 4; ii++) {
        int j = ty + 8 * ii;
        int c = c0 + j;
        int g = c / HID, d = c % HID;
        float w = tile[tx][j];
        unsigned short hi = f2bf(w);
        unsigned short lo = f2bf(w - bf2f(hi));
        size_t o = (size_t)(4 * d + g) * HID + k0 + tx;
        ohi[o] = hi;
        olo[o] = lo;
    }
}

// mix_W [512][123] fp32 -> [128][512] bf16 (zero padded cols >=123)
__global__ void k_pack_mix(const float* __restrict__ W, unsigned short* __restrict__ out) {
    int idx = blockIdx.x * 256 + threadIdx.x;  // 128*512
    int n = idx >> 9, k = idx & 511;
    out[idx] = (n < P) ? f2bf(W[(size_t)k * P + n]) : (unsigned short)0;
}

// generic fp32 column permutation into packed gate order: out[row][n] = in[row][(n&3)*HID + (n>>2)]
__global__ void k_pack_cols(const float* __restrict__ in, float* __restrict__ out, int HID, int N4) {
    int idx = blockIdx.x * 256 + threadIdx.x;
    int row = idx / N4, n = idx % N4;
    out[idx] = in[(size_t)row * N4 + (n & 3) * HID + (n >> 2)];
}

// ---------------- fused LSTM step (bf16x3): gates = h @ Wh + x@Wx + bias; pointwise update ----------------
struct StepArgs {
    const unsigned short* hprev_hi[2];
    const unsigned short* hprev_lo[2];
    unsigned short* hnext_hi[2];
    unsigned short* hnext_lo[2];
    float* c32[2];
    const unsigned short* wh_hi[2];
    const unsigned short* wh_lo[2];
    const float* bp[2];     // packed bias [4*HID] or nullptr
    const float* xbias[2];  // packed per-(b,col) bias (decoder zg) or nullptr
    const float* wxp[2];    // packed [5][4*HID]
    const float* xrow[2];   // data + tt*5 (per-batch stride 5*(T+1))
};

template <int HID>
__global__ __launch_bounds__(256) void k_lstm_step(StepArgs args) {
    constexpr int N4 = 4 * HID;
    int zi = blockIdx.z;
    const unsigned short* __restrict__ hp_hi = args.hprev_hi[zi];
    const unsigned short* __restrict__ hp_lo = args.hprev_lo[zi];
    unsigned short* __restrict__ hn_hi = args.hnext_hi[zi];
    unsigned short* __restrict__ hn_lo = args.hnext_lo[zi];
    float* __restrict__ c32 = args.c32[zi];
    const unsigned short* __restrict__ whi = args.wh_hi[zi];
    const unsigned short* __restrict__ wlo = args.wh_lo[zi];
    const float* __restrict__ bp = args.bp[zi];
    const float* __restrict__ xbias = args.xbias[zi];
    const float* __restrict__ wxp = args.wxp[zi];
    const float* __restrict__ xrow = args.xrow[zi];

    int tid = threadIdx.x;
    int wave = tid >> 6, lane = tid & 63;
    int q = lane >> 4, r = lane & 15;
    int m0 = blockIdx.y * 64 + (wave >> 1) * 32;
    int n0 = blockIdx.x * 64 + (wave & 1) * 32;

    f32x4 acc[2][2];
#pragma unroll
    for (int mi = 0; mi < 2; mi++)
#pragma unroll
        for (int ni = 0; ni < 2; ni++) acc[mi][ni] = {0.f, 0.f, 0.f, 0.f};

#pragma unroll 2
    for (int kk = 0; kk < HID; kk += 32) {
        int kb = kk + q * 8;
        short8 a0h = *(const short8*)(hp_hi + (size_t)(m0 + r) * HID + kb);
        short8 a1h = *(const short8*)(hp_hi + (size_t)(m0 + 16 + r) * HID + kb);
        short8 a0l = *(const short8*)(hp_lo + (size_t)(m0 + r) * HID + kb);
        short8 a1l = *(const short8*)(hp_lo + (size_t)(m0 + 16 + r) * HID + kb);
        short8 b0h = *(const short8*)(whi + (size_t)(n0 + r) * HID + kb);
        short8 b1h = *(const short8*)(whi + (size_t)(n0 + 16 + r) * HID + kb);
        short8 b0l = *(const short8*)(wlo + (size_t)(n0 + r) * HID + kb);
        short8 b1l = *(const short8*)(wlo + (size_t)(n0 + 16 + r) * HID + kb);
        // bf16x3: hi*hi + lo*hi + hi*lo  (lo*lo term ~2^-18, dropped)
        acc[0][0] = __builtin_amdgcn_mfma_f32_16x16x32_bf16(a0h, b0h, acc[0][0], 0, 0, 0);
        acc[0][1] = __builtin_amdgcn_mfma_f32_16x16x32_bf16(a0h, b1h, acc[0][1], 0, 0, 0);
        acc[1][0] = __builtin_amdgcn_mfma_f32_16x16x32_bf16(a1h, b0h, acc[1][0], 0, 0, 0);
        acc[1][1] = __builtin_amdgcn_mfma_f32_16x16x32_bf16(a1h, b1h, acc[1][1], 0, 0, 0);
        acc[0][0] = __builtin_amdgcn_mfma_f32_16x16x32_bf16(a0l, b0h, acc[0][0], 0, 0, 0);
        acc[0][1] = __builtin_amdgcn_mfma_f32_16x16x32_bf16(a0l, b1h, acc[0][1], 0, 0, 0);
        acc[1][0] = __builtin_amdgcn_mfma_f32_16x16x32_bf16(a1l, b0h, acc[1][0], 0, 0, 0);
        acc[1][1] = __builtin_amdgcn_mfma_f32_16x16x32_bf16(a1l, b1h, acc[1][1], 0, 0, 0);
        acc[0][0] = __builtin_amdgcn_mfma_f32_16x16x32_bf16(a0h, b0l, acc[0][0], 0, 0, 0);
        acc[0][1] = __builtin_amdgcn_mfma_f32_16x16x32_bf16(a0h, b1l, acc[0][1], 0, 0, 0);
        acc[1][0] = __builtin_amdgcn_mfma_f32_16x16x32_bf16(a1h, b0l, acc[1][0], 0, 0, 0);
        acc[1][1] = __builtin_amdgcn_mfma_f32_16x16x32_bf16(a1h, b1l, acc[1][1], 0, 0, 0);
    }

#pragma unroll
    for (int ni = 0; ni < 2; ni++) {
        int ncol = n0 + ni * 16 + r;
        int g = ncol & 3, d = ncol >> 2;
        float bias = bp ? bp[ncol] : 0.0f;
        float w0 = wxp[0 * N4 + ncol], w1 = wxp[1 * N4 + ncol], w2 = wxp[2 * N4 + ncol];
        float w3 = wxp[3 * N4 + ncol], w4 = wxp[4 * N4 + ncol];
#pragma unroll
        for (int mi = 0; mi < 2; mi++) {
#pragma unroll
            for (int rr = 0; rr < 4; rr++) {
                int b = m0 + mi * 16 + q * 4 + rr;
                float v = acc[mi][ni][rr] + bias;
                const float* xr = xrow + (size_t)b * (5 * (T + 1));
                v += xr[0] * w0 + xr[1] * w1 + xr[2] * w2 + xr[3] * w3 + xr[4] * w4;
                if (xbias) v += xbias[(size_t)b * N4 + ncol];
                float s1 = __shfl_xor(v, 1, 64);
                float s2 = __shfl_xor(v, 2, 64);
                float s3 = __shfl_xor(v, 3, 64);
                float gi, gf, gg, go;
                if (g == 0)      { gi = v;  gf = s1; gg = s2; go = s3; }
                else if (g == 1) { gi = s1; gf = v;  gg = s3; go = s2; }
                else if (g == 2) { gi = s2; gf = s3; gg = v;  go = s1; }
                else             { gi = s3; gf = s2; gg = s1; go = v;  }
                float cold = c32[(size_t)b * HID + d];
                float cnew = sigm(gf) * cold + sigm(gi) * tanh_(gg);
                float hnew = sigm(go) * tanh_(cnew);
                if (g == 0) {
                    c32[(size_t)b * HID + d] = cnew;
                } else if (g == 1) {
                    hn_hi[(size_t)b * HID + d] = f2bf(hnew);
                } else if (g == 2) {
                    unsigned short hi = f2bf(hnew);
                    hn_lo[(size_t)b * HID + d] = f2bf(hnew - bf2f(hi));
                }
            }
        }
    }
}

// ---------------- encoder output -> z_mean, z_logvar, z ----------------
__global__ void k_encout(const unsigned short* __restrict__ hfh, const unsigned short* __restrict__ hfl,
                         const unsigned short* __restrict__ hbh, const unsigned short* __restrict__ hbl,
                         const float* __restrict__ W, const float* __restrict__ bias,
                         const float* __restrict__ eps, float* __restrict__ dout,
                         float* __restrict__ zbuf) {
    __shared__ float hc[2 * H];
    int b = blockIdx.x, tid = threadIdx.x;  // 128 threads
    hc[tid]       = bf2f(hfh[(size_t)b * H + tid])       + bf2f(hfl[(size_t)b * H + tid]);
    hc[tid + 128] = bf2f(hfh[(size_t)b * H + tid + 128]) + bf2f(hfl[(size_t)b * H + tid + 128]);
    hc[tid + 256] = bf2f(hbh[(size_t)b * H + tid])       + bf2f(hbl[(size_t)b * H + tid]);
    hc[tid + 384] = bf2f(hbh[(size_t)b * H + tid + 128]) + bf2f(hbl[(size_t)b * H + tid + 128]);
    __syncthreads();
    float mean = bias[tid], lv = bias[Z + tid];
    for (int k = 0; k < 2 * H; k++) {
        float h = hc[k];
        mean += h * W[(size_t)k * 2 * Z + tid];
        lv += h * W[(size_t)k * 2 * Z + Z + tid];
    }
    float z = mean + __expf(0.5f * lv) * eps[(size_t)b * Z + tid];
    dout[OUT_ZM + (size_t)b * Z + tid] = mean;
    dout[OUT_ZL + (size_t)b * Z + tid] = lv;
    zbuf[(size_t)b * Z + tid] = z;
}

// ---------------- decoder init: tanh(z @ init_W + init_b) -> h0 (hi/lo), c0 (fp32) ----------------
__global__ void k_init_dec(const float* __restrict__ zbuf, const float* __restrict__ iW,
                           const float* __restrict__ ib, unsigned short* __restrict__ hs0_hi,
                           unsigned short* __restrict__ hs0_lo, float* __restrict__ c32) {
    __shared__ float zsh[16][Z];
    int c = blockIdx.x * 256 + threadIdx.x;  // 0..1023
    int b0 = blockIdx.y * 16;
    for (int i = threadIdx.x; i < 16 * Z; i += 256) zsh[i >> 7][i & 127] = zbuf[(size_t)(b0 + (i >> 7)) * Z + (i & 127)];
    __syncthreads();
    float acc[16];
    float bias = ib[c];
#pragma unroll
    for (int bb = 0; bb < 16; bb++) acc[bb] = bias;
    for (int k = 0; k < Z; k++) {
        float w = iW[(size_t)k * 1024 + c];
#pragma unroll
        for (int bb = 0; bb < 16; bb++) acc[bb] += zsh[bb][k] * w;
    }
    for (int bb = 0; bb < 16; bb++) {
        float v = tanh_(acc[bb]);
        int b = b0 + bb;
        if (c < D) {
            unsigned short hi = f2bf(v);
            hs0_hi[(size_t)b * D + c] = hi;
            hs0_lo[(size_t)b * D + c] = f2bf(v - bf2f(hi));
        } else {
            c32[(size_t)b * D + (c - D)] = v;
        }
    }
}

// ---------------- zg = z @ Wx_z + dec_b, packed columns ----------------
__global__ void k_zg(const float* __restrict__ zbuf, const float* __restrict__ dwx,
                     const float* __restrict__ db, float* __restrict__ zg) {
    __shared__ float zsh[16][Z];
    int c = blockIdx.x * 256 + threadIdx.x;  // 0..2047
    int b0 = blockIdx.y * 16;
    for (int i = threadIdx.x; i < 16 * Z; i += 256) zsh[i >> 7][i & 127] = zbuf[(size_t)(b0 + (i >> 7)) * Z + (i & 127)];
    __syncthreads();
    float acc[16];
    float bias = db[c];
#pragma unroll
    for (int bb = 0; bb < 16; bb++) acc[bb] = bias;
    for (int k = 0; k < Z; k++) {
        float w = dwx[(size_t)(5 + k) * 2048 + c];
#pragma unroll
        for (int bb = 0; bb < 16; bb++) acc[bb] += zsh[bb][k] * w;
    }
    int n = 4 * (c & 511) + (c >> 9);
#pragma unroll
    for (int bb = 0; bb < 16; bb++) zg[(size_t)(b0 + bb) * 2048 + n] = acc[bb];
}

// ---------------- mix GEMM: y[b][t][p] = hs[t][b][:] @ mixWT + mix_b ----------------
__global__ __launch_bounds__(256) void k_mix(const unsigned short* __restrict__ hs,
                                             const unsigned short* __restrict__ mixwt,
                                             const float* __restrict__ mb, float* __restrict__ dout) {
    int tid = threadIdx.x, wave = tid >> 6, lane = tid & 63, q = lane >> 4, r = lane & 15;
    int m0 = blockIdx.y * 64 + (wave >> 1) * 32;
    int n0 = blockIdx.x * 64 + (wave & 1) * 32;
    const unsigned short* A = hs + (size_t)B * D;  // slot 1 = h_0 output
    f32x4 acc[2][2];
#pragma unroll
    for (int mi = 0; mi < 2; mi++)
#pragma unroll
        for (int ni = 0; ni < 2; ni++) acc[mi][ni] = {0.f, 0.f, 0.f, 0.f};
#pragma unroll 4
    for (int kk = 0; kk < D; kk += 32) {
        int kb = kk + q * 8;
        short8 a0 = *(const short8*)(A + (size_t)(m0 + r) * D + kb);
        short8 a1 = *(const short8*)(A + (size_t)(m0 + 16 + r) * D + kb);
        short8 b0 = *(const short8*)(mixwt + (size_t)(n0 + r) * D + kb);
        short8 b1 = *(const short8*)(mixwt + (size_t)(n0 + 16 + r) * D + kb);
        acc[0][0] = __builtin_amdgcn_mfma_f32_16x16x32_bf16(a0, b0, acc[0][0], 0, 0, 0);
        acc[0][1] = __builtin_amdgcn_mfma_f32_16x16x32_bf16(a0, b1, acc[0][1], 0, 0, 0);
        acc[1][0] = __builtin_amdgcn_mfma_f32_16x16x32_bf16(a1, b0, acc[1][0], 0, 0, 0);
        acc[1][1] = __builtin_amdgcn_mfma_f32_16x16x32_bf16(a1, b1, acc[1][1], 0, 0, 0);
    }
#pragma unroll
    for (int ni = 0; ni < 2; ni++) {
        int ncol = n0 + ni * 16 + r;
        if (ncol < P) {
            float bias = mb[ncol];
#pragma unroll
            for (int mi = 0; mi < 2; mi++) {
#pragma unroll
                for (int rr = 0; rr < 4; rr++) {
                    int m = m0 + mi * 16 + q * 4 + rr;
                    int b = m & 255, t = m >> 8;
                    dout[((size_t)b * T + t) * P + ncol] = acc[mi][ni][rr] + bias;
                }
            }
        }
    }
}

// ---------------- in-place per-row epilogue: softmax(pi), exp(sigma), tanh(rho) ----------------
__global__ void k_post(float* __restrict__ dout) {
    __shared__ float row[P];
    int rid = blockIdx.x;  // 64000 rows
    int tid = threadIdx.x; // 128
    float* base = dout + (size_t)rid * P;
    float v = 0.f;
    if (tid < P) { v = base[tid]; row[tid] = v; }
    __syncthreads();
    if (tid < P) {
        float o;
        if (tid < KMIX) {
            float mx = row[0];
            for (int i = 1; i < KMIX; i++) mx = fmaxf(mx, row[i]);
            float sm = 0.f;
            for (int i = 0; i < KMIX; i++) sm += __expf(row[i] - mx);
            o = __expf(v - mx) / sm;
        } else if (tid < 3 * KMIX) o = v;
        else if (tid < 5 * KMIX) o = __expf(v);
        else if (tid < 6 * KMIX) o = tanh_(v);
        else o = v;
        base[tid] = o;
    }
}

extern "C" void kernel_launch(void* const* d_in, const int* in_sizes, int n_in,
                              void* d_out, int out_size, void* d_ws, size_t ws_size,
                              hipStream_t stream) {
    const float* data = (const float*)d_in[0];
    const float* eps  = (const float*)d_in[1];
    const float* eWxf = (const float*)d_in[2];
    const float* eWhf = (const float*)d_in[3];
    const float* ebf  = (const float*)d_in[4];
    const float* eWxb = (const float*)d_in[5];
    const float* eWhb = (const float*)d_in[6];
    const float* ebb  = (const float*)d_in[7];
    const float* eoW  = (const float*)d_in[8];
    const float* eob  = (const float*)d_in[9];
    const float* iW   = (const float*)d_in[10];
    const float* ib   = (const float*)d_in[11];
    const float* dWx  = (const float*)d_in[12];
    const float* dWh  = (const float*)d_in[13];
    const float* db   = (const float*)d_in[14];
    const float* mW   = (const float*)d_in[15];
    const float* mb   = (const float*)d_in[16];
    float* out = (float*)d_out;

    char* base = (char*)d_ws;
    size_t off = 0;
    auto alloc = [&](size_t bytes) -> char* {
        off = (off + 255) & ~(size_t)255;
        char* p = base + off;
        off += bytes;
        return p;
    };
    unsigned short* whd_hi = (unsigned short*)alloc((size_t)2048 * 512 * 2);
    unsigned short* whd_lo = (unsigned short*)alloc((size_t)2048 * 512 * 2);
    unsigned short* whf_hi = (unsigned short*)alloc((size_t)1024 * 256 * 2);
    unsigned short* whf_lo = (unsigned short*)alloc((size_t)1024 * 256 * 2);
    unsigned short* whb_hi = (unsigned short*)alloc((size_t)1024 * 256 * 2);
    unsigned short* whb_lo = (unsigned short*)alloc((size_t)1024 * 256 * 2);
    unsigned short* mixwt  = (unsigned short*)alloc((size_t)128 * 512 * 2);
    float* wxp_dec = (float*)alloc((size_t)5 * 2048 * 4);
    float* wxp_ef  = (float*)alloc((size_t)5 * 1024 * 4);
    float* wxp_eb  = (float*)alloc((size_t)5 * 1024 * 4);
    float* bp_ef   = (float*)alloc((size_t)1024 * 4);
    float* bp_eb   = (float*)alloc((size_t)1024 * 4);
    unsigned short* hf_hi = (unsigned short*)alloc((size_t)2 * B * H * 2);
    unsigned short* hf_lo = (unsigned short*)alloc((size_t)2 * B * H * 2);
    unsigned short* hb_hi = (unsigned short*)alloc((size_t)2 * B * H * 2);
    unsigned short* hb_lo = (unsigned short*)alloc((size_t)2 * B * H * 2);
    float* c32_ef = (float*)alloc((size_t)B * H * 4);
    float* c32_eb = (float*)alloc((size_t)B * H * 4);
    float* c32_d  = (float*)alloc((size_t)B * D * 4);
    unsigned short* hs_hi = (unsigned short*)alloc((size_t)(T + 1) * B * D * 2);
    unsigned short* hlo_pp = (unsigned short*)alloc((size_t)2 * B * D * 2);
    float* zbuf = (float*)alloc((size_t)B * Z * 4);
    float* zg   = (float*)alloc((size_t)B * 2048 * 4);
    (void)ws_size; (void)in_sizes; (void)n_in; (void)out_size;

    // ---- init + packing ----
    k_zero<<<256, 256, 0, stream>>>(c32_ef, c32_eb, hf_hi, hb_hi, hf_lo, hb_lo);
    k_pack_whT<512><<<dim3(64, 16), dim3(32, 8), 0, stream>>>(dWh, whd_hi, whd_lo);
    k_pack_whT<256><<<dim3(32, 8), dim3(32, 8), 0, stream>>>(eWhf, whf_hi, whf_lo);
    k_pack_whT<256><<<dim3(32, 8), dim3(32, 8), 0, stream>>>(eWhb, whb_hi, whb_lo);
    k_pack_mix<<<256, 256, 0, stream>>>(mW, mixwt);
    k_pack_cols<<<40, 256, 0, stream>>>(dWx, wxp_dec, 512, 2048);
    k_pack_cols<<<20, 256, 0, stream>>>(eWxf, wxp_ef, 256, 1024);
    k_pack_cols<<<20, 256, 0, stream>>>(eWxb, wxp_eb, 256, 1024);
    k_pack_cols<<<4, 256, 0, stream>>>(ebf, bp_ef, 256, 1024);
    k_pack_cols<<<4, 256, 0, stream>>>(ebb, bp_eb, 256, 1024);

    // ---- encoder: 250 steps, fwd (z=0) and bwd (z=1) in one launch ----
    for (int t = 0; t < T; t++) {
        StepArgs a{};
        int pi = t & 1, po = (t + 1) & 1;
        a.hprev_hi[0] = hf_hi + (size_t)pi * B * H;
        a.hprev_lo[0] = hf_lo + (size_t)pi * B * H;
        a.hnext_hi[0] = hf_hi + (size_t)po * B * H;
        a.hnext_lo[0] = hf_lo + (size_t)po * B * H;
        a.c32[0] = c32_ef;
        a.wh_hi[0] = whf_hi;
        a.wh_lo[0] = whf_lo;
        a.bp[0] = bp_ef;
        a.xbias[0] = nullptr;
        a.wxp[0] = wxp_ef;
        a.xrow[0] = data + (size_t)(1 + t) * 5;
        a.hprev_hi[1] = hb_hi + (size_t)pi * B * H;
        a.hprev_lo[1] = hb_lo + (size_t)pi * B * H;
        a.hnext_hi[1] = hb_hi + (size_t)po * B * H;
        a.hnext_lo[1] = hb_lo + (size_t)po * B * H;
        a.c32[1] = c32_eb;
        a.wh_hi[1] = whb_hi;
        a.wh_lo[1] = whb_lo;
        a.bp[1] = bp_eb;
        a.xbias[1] = nullptr;
        a.wxp[1] = wxp_eb;
        a.xrow[1] = data + (size_t)(250 - t) * 5;
        k_lstm_step<256><<<dim3(16, 4, 2), 256, 0, stream>>>(a);
    }

    // ---- z, decoder init, zg ----
    k_encout<<<256, 128, 0, stream>>>(hf_hi, hf_lo, hb_hi, hb_lo, eoW, eob, eps, out, zbuf);
    k_init_dec<<<dim3(4, 16), 256, 0, stream>>>(zbuf, iW, ib, hs_hi, hlo_pp, c32_d);
    k_zg<<<dim3(8, 16), 256, 0, stream>>>(zbuf, dWx, db, zg);

    // ---- decoder: 250 steps ----
    for (int t = 0; t < T; t++) {
        StepArgs a{};
        a.hprev_hi[0] = hs_hi + (size_t)t * B * D;
        a.hprev_lo[0] = hlo_pp + (size_t)(t & 1) * B * D;
        a.hnext_hi[0] = hs_hi + (size_t)(t + 1) * B * D;
        a.hnext_lo[0] = hlo_pp + (size_t)((t + 1) & 1) * B * D;
        a.c32[0] = c32_d;
        a.wh_hi[0] = whd_hi;
        a.wh_lo[0] = whd_lo;
        a.bp[0] = nullptr;
        a.xbias[0] = zg;
        a.wxp[0] = wxp_dec;
        a.xrow[0] = data + (size_t)t * 5;
        k_lstm_step<512><<<dim3(32, 4, 1), 256, 0, stream>>>(a);
    }

    // ---- mix head + in-place epilogue ----
    k_mix<<<dim3(2, 1000), 256, 0, stream>>>(hs_hi, mixwt, mb, out);
    k_post<<<64000, 128, 0, stream>>>(out);
}